// Round 4
// baseline (269.234 us; speedup 1.0000x reference)
//
#include <hip/hip_runtime.h>

#define NQ 16

// complex multiply: (rr,ri) = (ar,ai)*(br,bi)  (safe for aliasing)
#define CMUL(rr, ri, ar, ai, br, bi) do { \
  const float _tr = (ar)*(br) - (ai)*(bi); \
  const float _ti = (ar)*(bi) + (ai)*(br); \
  (rr) = _tr; (ri) = _ti; } while (0)

// u_q = RY(p1[q]) * RX(xs[q]) * |0>:  u0=(cp*cx, sp*sx), u1=(sp*cx, -cp*sx)
#define MAKE_U(q, U0R, U0I, U1R, U1I) \
  float U0R, U0I, U1R, U1I; { \
    float sx_, cx_; __sincosf(xs[(q)] * 0.5f, &sx_, &cx_); \
    float sp_, cp_; __sincosf(p1[(q)] * 0.5f, &sp_, &cp_); \
    U0R = cp_ * cx_; U0I = sp_ * sx_; U1R = sp_ * cx_; U1I = -cp_ * sx_; }

// w[j] = u[j ^ sb]
#define SWAP_U(sb, U0R, U0I, U1R, U1I, W0R, W0I, W1R, W1I) \
  float W0R, W0I, W1R, W1I; { \
    W0R = (sb) ? (U1R) : (U0R); W0I = (sb) ? (U1I) : (U0I); \
    W1R = (sb) ? (U0R) : (U1R); W1I = (sb) ? (U0I) : (U1I); }

// RY butterfly on register-bit k, with per-lane role-flip f absorbed as a sign on sin
#define STAGE(q, k, f) { \
    float sn_, cs_; __sincosf(p2[(q)] * 0.5f, &sn_, &cs_); \
    const float se_ = (f) ? sn_ : -sn_; \
    _Pragma("unroll") \
    for (int r = 0; r < 64; ++r) { \
      if (!(r & (1 << (k)))) { \
        const float xv_ = s[r], yv_ = s[r + (1 << (k))]; \
        s[r]              = cs_ * xv_ + se_ * yv_; \
        s[r + (1 << (k))] = cs_ * yv_ - se_ * xv_; \
      } \
    } \
  }

// R2/R3 post-mortem: the VGPR budget follows the backend's LDS-derived
// occupancy target. At 64 KB LDS, 2 blocks/CU fit (128<=160 KB) -> 8 waves/EU
// -> 64 VGPRs -> s[64] spills to scratch (660 MB HBM, the entire 224 us).
// waves_per_eu(4,4) alone did NOT override it (R3: VGPR still 64).
// Fix: pad LDS to 96 KB so only ONE block fits per CU (96 > 160-96). Then
// LDS-occupancy = 16 waves/CU = 4 waves/EU -> VGPR budget 512/4 = 128, and the
// ~105-reg live set fits with no spill. gfx950 addressable LDS = 160 KB.
__global__
__attribute__((amdgpu_flat_work_group_size(1024, 1024)))
__attribute__((amdgpu_waves_per_eu(4, 4)))
void qsim_kernel(const float* __restrict__ x, const float* __restrict__ params,
                 float* __restrict__ out) {
  const int sample = blockIdx.x;
  const int tid = threadIdx.x;
  const int w = tid >> 6;   // wave 0..15
  const int l = tid & 63;   // lane 0..63

  const int w3 = (w >> 3) & 1, w2b = (w >> 2) & 1, w1b = (w >> 1) & 1, w0b = w & 1;
  const int l5 = (l >> 5) & 1, l4 = (l >> 4) & 1, l3 = (l >> 3) & 1;
  const int l2 = (l >> 2) & 1, l1 = (l >> 1) & 1, l0 = l & 1;

  // 24576 floats = 96 KB: only 64 KB is used; the pad exists purely to force
  // 1 block/CU so the register allocator budgets 128 VGPRs (see note above).
  __shared__ __align__(16) float lds[24576];

  const float* xs = x + sample * NQ;
  const float* p1 = params;       // layer-1 RY angles
  const float* p2 = params + NQ;  // layer-2 RY angles

  // M^{-1} select bits for the thread-fixed prefix product (qubits 2..9).
  // Init layout: i = [w(4) | l(6) | slot(6)], qubit q <-> index bit 15-q.
  const int a_2 = w2b ^ w1b, a_3 = w1b ^ w0b, a_4 = w0b ^ l5, a_5 = l5 ^ l4;
  const int a_6 = l4 ^ l3,  a_7 = l3 ^ l2,  a_8 = l2 ^ l1,  a_9 = l1 ^ l0;

  float acc = 0.0f;   // wave w, lane 0 accumulates <Z_w> across planes
  float s[64];

  for (int plane = 0; plane < 2; ++plane) {
    // ---------------- init: ring-1-permuted product state ----------------
    float Pr = 1.0f, Pi = 0.0f;
    {
      const int abits[8] = {a_2, a_3, a_4, a_5, a_6, a_7, a_8, a_9};
      #pragma unroll
      for (int qi = 0; qi < 8; ++qi) {
        const int q = qi + 2;
        float sx_, cx_; __sincosf(xs[q] * 0.5f, &sx_, &cx_);
        float sp_, cp_; __sincosf(p1[q] * 0.5f, &sp_, &cp_);
        const float u0r = cp_ * cx_, u0i = sp_ * sx_;
        const float u1r = sp_ * cx_, u1i = -cp_ * sx_;
        const float ar = abits[qi] ? u1r : u0r;
        const float ai = abits[qi] ? u1i : u0i;
        CMUL(Pr, Pi, Pr, Pi, ar, ai);
      }
    }

    // Register-slot invariant pre-T2: actual_slot = reg ^ (l5<<5 | l4<<4).
    float TAr[4], TAi[4], TBr[4], TBi[4], g2r[8], g2i[8];
    {
      MAKE_U(10, uA0r, uA0i, uA1r, uA1i);
      SWAP_U(l0 ^ l5, uA0r, uA0i, uA1r, uA1i, wA0r, wA0i, wA1r, wA1i);
      MAKE_U(11, uB0r, uB0i, uB1r, uB1i);
      SWAP_U(l5 ^ l4, uB0r, uB0i, uB1r, uB1i, wB0r, wB0i, wB1r, wB1i);
      // TA[h5*2+h4] = wA[h5] * wB[h5^h4]
      CMUL(TAr[0], TAi[0], wA0r, wA0i, wB0r, wB0i);
      CMUL(TAr[1], TAi[1], wA0r, wA0i, wB1r, wB1i);
      CMUL(TAr[2], TAi[2], wA1r, wA1i, wB1r, wB1i);
      CMUL(TAr[3], TAi[3], wA1r, wA1i, wB0r, wB0i);
    }
    {
      MAKE_U(12, uC0r, uC0i, uC1r, uC1i);
      SWAP_U(l4, uC0r, uC0i, uC1r, uC1i, wC0r, wC0i, wC1r, wC1i);
      MAKE_U(13, uD0r, uD0i, uD1r, uD1i);
      // TB[x*2+y] = wC[x]*u13[y],  x = h4^h3, y = h3^h2
      CMUL(TBr[0], TBi[0], wC0r, wC0i, uD0r, uD0i);
      CMUL(TBr[1], TBi[1], wC0r, wC0i, uD1r, uD1i);
      CMUL(TBr[2], TBi[2], wC1r, wC1i, uD0r, uD0i);
      CMUL(TBr[3], TBi[3], wC1r, wC1i, uD1r, uD1i);
    }
    {
      MAKE_U(0, uE0r, uE0i, uE1r, uE1i);
      SWAP_U(w3, uE0r, uE0i, uE1r, uE1i, wD0r, wD0i, wD1r, wD1i);
      MAKE_U(1, uF0r, uF0i, uF1r, uF1i);
      SWAP_U(w3 ^ w2b, uF0r, uF0i, uF1r, uF1i, wE0r, wE0i, wE1r, wE1i);
      float d0r[2], d0i[2];
      CMUL(d0r[0], d0i[0], wD0r, wD0i, wE0r, wE0i);
      CMUL(d0r[0], d0i[0], d0r[0], d0i[0], Pr, Pi);
      CMUL(d0r[1], d0i[1], wD1r, wD1i, wE1r, wE1i);
      CMUL(d0r[1], d0i[1], d0r[1], d0i[1], Pr, Pi);
      MAKE_U(15, uG0r, uG0i, uG1r, uG1i);
      float d1r[4], d1i[4];  // d1[h1*2+h0] = u15[h1^h0]*d0[h0]
      CMUL(d1r[0], d1i[0], uG0r, uG0i, d0r[0], d0i[0]);
      CMUL(d1r[1], d1i[1], uG1r, uG1i, d0r[1], d0i[1]);
      CMUL(d1r[2], d1i[2], uG1r, uG1i, d0r[0], d0i[0]);
      CMUL(d1r[3], d1i[3], uG0r, uG0i, d0r[1], d0i[1]);
      MAKE_U(14, uH0r, uH0i, uH1r, uH1i);
      // g2[h2*4+h1*2+h0] = u14[h2^h1]*d1[h1*2+h0]
      CMUL(g2r[0], g2i[0], uH0r, uH0i, d1r[0], d1i[0]);
      CMUL(g2r[1], g2i[1], uH0r, uH0i, d1r[1], d1i[1]);
      CMUL(g2r[2], g2i[2], uH1r, uH1i, d1r[2], d1i[2]);
      CMUL(g2r[3], g2i[3], uH1r, uH1i, d1r[3], d1i[3]);
      CMUL(g2r[4], g2i[4], uH1r, uH1i, d1r[0], d1i[0]);
      CMUL(g2r[5], g2i[5], uH1r, uH1i, d1r[1], d1i[1]);
      CMUL(g2r[6], g2i[6], uH0r, uH0i, d1r[2], d1i[2]);
      CMUL(g2r[7], g2i[7], uH0r, uH0i, d1r[3], d1i[3]);
    }
    #pragma unroll
    for (int g = 0; g < 16; ++g) {
      const int h5 = (g >> 3) & 1, h4 = (g >> 2) & 1, h3 = (g >> 1) & 1, h2 = g & 1;
      const int ta = h5 * 2 + h4;
      const int tb = ((h4 ^ h3) << 1) | (h3 ^ h2);
      float g1r_, g1i_;
      CMUL(g1r_, g1i_, TAr[ta], TAi[ta], TBr[tb], TBi[tb]);
      #pragma unroll
      for (int t = 0; t < 4; ++t) {
        const int i7 = (h2 << 2) | t;
        const float re = g1r_ * g2r[i7] - g1i_ * g2i[i7];
        const float im = g1r_ * g2i[i7] + g1i_ * g2r[i7];
        s[g * 4 + t] = plane ? im : re;
      }
    }

    // ---------------- set 1: qubits 10..15 (slot bits 5..0) ----------------
    STAGE(10, 5, l5) STAGE(11, 4, l4) STAGE(12, 3, 0)
    STAGE(13, 2, 0)  STAGE(14, 1, 0)  STAGE(15, 0, 0)

    // ---------------- T1: in-wave lane<->slot transpose ----------------
    const int waveBase = w << 10;
    const int bp = l >> 4;
    const int kk = l & 15;
    #pragma unroll
    for (int d = 0; d < 4; ++d) {
      __syncthreads();
      #pragma unroll
      for (int k = 0; k < 16; ++k)
        lds[waveBase + k * 64 + (l ^ (k & 12))] = s[16 * d + k];
      __syncthreads();
      const int xb = 16 * (d ^ bp);
      #pragma unroll
      for (int j4 = 0; j4 < 4; ++j4) {
        const int xa = (xb + 4 * j4) ^ (kk & 12);
        const float4 v = *reinterpret_cast<const float4*>(&lds[waveBase + kk * 64 + xa]);
        s[16 * d + 4 * j4 + 0] = v.x;
        s[16 * d + 4 * j4 + 1] = v.y;
        s[16 * d + 4 * j4 + 2] = v.z;
        s[16 * d + 4 * j4 + 3] = v.w;
      }
    }

    // ---------------- set 2: qubits 4..9 (slot bits 5..0) ----------------
    STAGE(4, 5, l5) STAGE(5, 4, l4) STAGE(6, 3, 0)
    STAGE(7, 2, 0)  STAGE(8, 1, 0)  STAGE(9, 0, 0)

    // ---------------- T2: cross-wave swap (wave bits <-> slot bits 5..2) ----------------
    #pragma unroll
    for (int c = 0; c < 4; ++c) {
      __syncthreads();
      #pragma unroll
      for (int m = 0; m < 16; ++m) {
        const int mact = m ^ (l5 << 3) ^ (l4 << 2);   // undo register xor invariant
        lds[(w << 10) + mact * 64 + l] = s[4 * m + c];
      }
      __syncthreads();
      #pragma unroll
      for (int g = 0; g < 16; ++g)
        s[4 * g + c] = lds[(g << 10) + (w << 6) + l];  // clean: reg == actual from here
    }

    // ---------------- set 3: qubits 0..3 (slot bits 5..2) ----------------
    STAGE(0, 5, 0) STAGE(1, 4, 0) STAGE(2, 3, 0) STAGE(3, 2, 0)

    // ---------------- measurement: partial Walsh fold ----------------
    // Final layout: qubit bits: b0..b3 = slot5..2, b4..b7 = w3..w0, b8,b9 = slot1,0,
    // b10..b15 = l5..l0. Ring-2 absorbed: mask_q = prefix parity.
    float alpha[4], beta[4], gammav[4], deltav[4], epsv[4];
    #pragma unroll
    for (int b = 0; b < 4; ++b) {
      float p0[16];
      #pragma unroll
      for (int o = 0; o < 16; ++o) { const float vv = s[16 * b + o]; p0[o] = vv * vv; }
      float tt[8], uu[8];
      #pragma unroll
      for (int o = 0; o < 8; ++o) { tt[o] = p0[2*o] + p0[2*o+1]; uu[o] = p0[2*o] - p0[2*o+1]; }
      float ts[4], td[4], ud[4];
      #pragma unroll
      for (int o = 0; o < 4; ++o) { ts[o] = tt[2*o] + tt[2*o+1]; td[o] = tt[2*o] - tt[2*o+1]; ud[o] = uu[2*o] - uu[2*o+1]; }
      float tss[2], tsd[2], tdd[2], udd[2];
      #pragma unroll
      for (int o = 0; o < 2; ++o) { tss[o] = ts[2*o] + ts[2*o+1]; tsd[o] = ts[2*o] - ts[2*o+1]; tdd[o] = td[2*o] - td[2*o+1]; udd[o] = ud[2*o] - ud[2*o+1]; }
      alpha[b]  = tss[0] + tss[1];
      beta[b]   = tss[0] - tss[1];
      gammav[b] = tsd[0] - tsd[1];
      deltav[b] = tdd[0] - tdd[1];
      epsv[b]   = udd[0] - udd[1];
    }
    const float TA_ = (alpha[0]  - alpha[1])  - (alpha[2]  - alpha[3]);
    const float TB_ = (beta[0]   - beta[1])   - (beta[2]   - beta[3]);
    const float TC_ = (gammav[0] - gammav[1]) - (gammav[2] - gammav[3]);
    const float TD_ = (deltav[0] - deltav[1]) - (deltav[2] - deltav[3]);
    const float TE_ = (epsv[0]   - epsv[1])   - (epsv[2]   - epsv[3]);
    const float TF_ = (epsv[0]   - epsv[1])   + (epsv[2]   - epsv[3]);

    const int pw1 = w3, pw2 = w3 ^ w2b, pw3 = w3 ^ w2b ^ w1b, pw4 = w3 ^ w2b ^ w1b ^ w0b;
    const int pl1 = l5, pl2 = pl1 ^ l4, pl3 = pl2 ^ l3, pl4 = pl3 ^ l2, pl5 = pl4 ^ l1, pl6 = pl5 ^ l0;

    float part[16];
    part[0]  = (pw4 ^ pl6) ? -TF_ : TF_;
    part[1]  = TA_;
    part[2]  = TB_;
    part[3]  = TC_;
    part[4]  = pw1 ? -TC_ : TC_;
    part[5]  = pw2 ? -TC_ : TC_;
    part[6]  = pw3 ? -TC_ : TC_;
    part[7]  = pw4 ? -TC_ : TC_;
    part[8]  = pw4 ? -TD_ : TD_;
    part[9]  = pw4 ? -TE_ : TE_;
    part[10] = (pw4 ^ pl1) ? -TE_ : TE_;
    part[11] = (pw4 ^ pl2) ? -TE_ : TE_;
    part[12] = (pw4 ^ pl3) ? -TE_ : TE_;
    part[13] = (pw4 ^ pl4) ? -TE_ : TE_;
    part[14] = (pw4 ^ pl5) ? -TE_ : TE_;
    part[15] = (pw4 ^ pl6) ? -TE_ : TE_;

    // ---------------- block reduction: wave q reduces output q ----------------
    __syncthreads();
    #pragma unroll
    for (int q = 0; q < 16; ++q)
      lds[(w << 10) + (q << 6) + l] = part[q];
    __syncthreads();
    float v = 0.0f;
    #pragma unroll
    for (int w2_ = 0; w2_ < 16; ++w2_)
      v += lds[(w2_ << 10) + (w << 6) + l];
    #pragma unroll
    for (int off = 32; off >= 1; off >>= 1)
      v += __shfl_xor(v, off, 64);
    acc += v;
  }

  if (l == 0) out[sample * NQ + w] = acc;
}

extern "C" void kernel_launch(void* const* d_in, const int* in_sizes, int n_in,
                              void* d_out, int out_size, void* d_ws, size_t ws_size,
                              hipStream_t stream) {
  (void)in_sizes; (void)n_in; (void)d_ws; (void)ws_size; (void)out_size;
  const float* x = (const float*)d_in[0];       // (512, 16) fp32
  const float* params = (const float*)d_in[1];  // (32,) fp32
  float* out = (float*)d_out;                   // (512, 16) fp32
  hipLaunchKernelGGL(qsim_kernel, dim3(512), dim3(1024), 0, stream, x, params, out);
}

// Round 5
// 268.687 us; speedup vs baseline: 1.0020x; 1.0020x over previous
//
#include <hip/hip_runtime.h>

#define NQ 16

// Compile-time for: induction variable is constexpr in the frontend AST, so
// SROA promotes every s[]-access before any mid-end unrolling runs.
// R4 post-mortem: runtime-indexed s[64] was never promoted (SROA bails on
// variable GEPs; AMDGPUPromoteAlloca refuses 64-elem vectors) -> alloca lived
// in scratch -> 660 MB HBM spill traffic regardless of occupancy attributes.
template <int I> struct ic { static constexpr int value = I; };
template <int N, int I = 0, typename F>
__device__ __forceinline__ void sfor(F&& f) {
  if constexpr (I < N) {
    f(ic<I>{});
    sfor<N, I + 1>(f);
  }
}

// complex multiply: (rr,ri) = (ar,ai)*(br,bi)  (safe for aliasing)
#define CMUL(rr, ri, ar, ai, br, bi) do { \
  const float _tr = (ar)*(br) - (ai)*(bi); \
  const float _ti = (ar)*(bi) + (ai)*(br); \
  (rr) = _tr; (ri) = _ti; } while (0)

// u_q = RY(p1[q]) * RX(xs[q]) * |0>:  u0=(cp*cx, sp*sx), u1=(sp*cx, -cp*sx)
#define MAKE_U(q, U0R, U0I, U1R, U1I) \
  float U0R, U0I, U1R, U1I; { \
    float sx_, cx_; __sincosf(xs[(q)] * 0.5f, &sx_, &cx_); \
    float sp_, cp_; __sincosf(p1[(q)] * 0.5f, &sp_, &cp_); \
    U0R = cp_ * cx_; U0I = sp_ * sx_; U1R = sp_ * cx_; U1I = -cp_ * sx_; }

// w[j] = u[j ^ sb]
#define SWAP_U(sb, U0R, U0I, U1R, U1I, W0R, W0I, W1R, W1I) \
  float W0R, W0I, W1R, W1I; { \
    W0R = (sb) ? (U1R) : (U0R); W0I = (sb) ? (U1I) : (U0I); \
    W1R = (sb) ? (U0R) : (U1R); W1I = (sb) ? (U0I) : (U1I); }

// RY butterfly on register-bit k (k = compile-time literal), role-flip f as sign
#define STAGE(q, k, f) { \
    float sn_, cs_; __sincosf(p2[(q)] * 0.5f, &sn_, &cs_); \
    const float se_ = (f) ? sn_ : -sn_; \
    sfor<32>([&](auto jc_) { \
      constexpr int j_ = decltype(jc_)::value; \
      constexpr int m_ = (1 << (k)) - 1; \
      constexpr int r_ = ((j_ & ~m_) << 1) | (j_ & m_); \
      const float xv_ = s[r_], yv_ = s[r_ + (1 << (k))]; \
      s[r_]              = cs_ * xv_ + se_ * yv_; \
      s[r_ + (1 << (k))] = cs_ * yv_ - se_ * xv_; \
    }); \
  }

// 96 KB LDS pad forces 1 block/CU -> 4 waves/EU -> 128-VGPR budget for the
// now-promoted ~110-reg live set. waves_per_eu(4,4) pins the same target.
__global__
__attribute__((amdgpu_flat_work_group_size(1024, 1024)))
__attribute__((amdgpu_waves_per_eu(4, 4)))
void qsim_kernel(const float* __restrict__ x, const float* __restrict__ params,
                 float* __restrict__ out) {
  const int sample = blockIdx.x;
  const int tid = threadIdx.x;
  const int w = tid >> 6;   // wave 0..15
  const int l = tid & 63;   // lane 0..63

  const int w3 = (w >> 3) & 1, w2b = (w >> 2) & 1, w1b = (w >> 1) & 1, w0b = w & 1;
  const int l5 = (l >> 5) & 1, l4 = (l >> 4) & 1, l3 = (l >> 3) & 1;
  const int l2 = (l >> 2) & 1, l1 = (l >> 1) & 1, l0 = l & 1;

  __shared__ __align__(16) float lds[24576];  // 96 KB (64 KB used; pad = occupancy pin)

  const float* xs = x + sample * NQ;
  const float* p1 = params;       // layer-1 RY angles
  const float* p2 = params + NQ;  // layer-2 RY angles

  // M^{-1} select bits for the thread-fixed prefix product (qubits 2..9).
  // Init layout: i = [w(4) | l(6) | slot(6)], qubit q <-> index bit 15-q.
  const int a_2 = w2b ^ w1b, a_3 = w1b ^ w0b, a_4 = w0b ^ l5, a_5 = l5 ^ l4;
  const int a_6 = l4 ^ l3,  a_7 = l3 ^ l2,  a_8 = l2 ^ l1,  a_9 = l1 ^ l0;

  float acc = 0.0f;   // wave w, lane 0 accumulates <Z_w> across planes
  float s[64];

  for (int plane = 0; plane < 2; ++plane) {
    // ---------------- init: ring-1-permuted product state ----------------
    float Pr = 1.0f, Pi = 0.0f;
    {
      const int abits[8] = {a_2, a_3, a_4, a_5, a_6, a_7, a_8, a_9};
      sfor<8>([&](auto qc_) {
        constexpr int qi = decltype(qc_)::value;
        constexpr int q = qi + 2;
        float sx_, cx_; __sincosf(xs[q] * 0.5f, &sx_, &cx_);
        float sp_, cp_; __sincosf(p1[q] * 0.5f, &sp_, &cp_);
        const float u0r = cp_ * cx_, u0i = sp_ * sx_;
        const float u1r = sp_ * cx_, u1i = -cp_ * sx_;
        const float ar = abits[qi] ? u1r : u0r;
        const float ai = abits[qi] ? u1i : u0i;
        CMUL(Pr, Pi, Pr, Pi, ar, ai);
      });
    }

    // Register-slot invariant pre-T2: actual_slot = reg ^ (l5<<5 | l4<<4).
    float TAr[4], TAi[4], TBr[4], TBi[4], g2r[8], g2i[8];
    {
      MAKE_U(10, uA0r, uA0i, uA1r, uA1i);
      SWAP_U(l0 ^ l5, uA0r, uA0i, uA1r, uA1i, wA0r, wA0i, wA1r, wA1i);
      MAKE_U(11, uB0r, uB0i, uB1r, uB1i);
      SWAP_U(l5 ^ l4, uB0r, uB0i, uB1r, uB1i, wB0r, wB0i, wB1r, wB1i);
      // TA[h5*2+h4] = wA[h5] * wB[h5^h4]
      CMUL(TAr[0], TAi[0], wA0r, wA0i, wB0r, wB0i);
      CMUL(TAr[1], TAi[1], wA0r, wA0i, wB1r, wB1i);
      CMUL(TAr[2], TAi[2], wA1r, wA1i, wB1r, wB1i);
      CMUL(TAr[3], TAi[3], wA1r, wA1i, wB0r, wB0i);
    }
    {
      MAKE_U(12, uC0r, uC0i, uC1r, uC1i);
      SWAP_U(l4, uC0r, uC0i, uC1r, uC1i, wC0r, wC0i, wC1r, wC1i);
      MAKE_U(13, uD0r, uD0i, uD1r, uD1i);
      // TB[x*2+y] = wC[x]*u13[y],  x = h4^h3, y = h3^h2
      CMUL(TBr[0], TBi[0], wC0r, wC0i, uD0r, uD0i);
      CMUL(TBr[1], TBi[1], wC0r, wC0i, uD1r, uD1i);
      CMUL(TBr[2], TBi[2], wC1r, wC1i, uD0r, uD0i);
      CMUL(TBr[3], TBi[3], wC1r, wC1i, uD1r, uD1i);
    }
    {
      MAKE_U(0, uE0r, uE0i, uE1r, uE1i);
      SWAP_U(w3, uE0r, uE0i, uE1r, uE1i, wD0r, wD0i, wD1r, wD1i);
      MAKE_U(1, uF0r, uF0i, uF1r, uF1i);
      SWAP_U(w3 ^ w2b, uF0r, uF0i, uF1r, uF1i, wE0r, wE0i, wE1r, wE1i);
      float d0r[2], d0i[2];
      CMUL(d0r[0], d0i[0], wD0r, wD0i, wE0r, wE0i);
      CMUL(d0r[0], d0i[0], d0r[0], d0i[0], Pr, Pi);
      CMUL(d0r[1], d0i[1], wD1r, wD1i, wE1r, wE1i);
      CMUL(d0r[1], d0i[1], d0r[1], d0i[1], Pr, Pi);
      MAKE_U(15, uG0r, uG0i, uG1r, uG1i);
      float d1r[4], d1i[4];  // d1[h1*2+h0] = u15[h1^h0]*d0[h0]
      CMUL(d1r[0], d1i[0], uG0r, uG0i, d0r[0], d0i[0]);
      CMUL(d1r[1], d1i[1], uG1r, uG1i, d0r[1], d0i[1]);
      CMUL(d1r[2], d1i[2], uG1r, uG1i, d0r[0], d0i[0]);
      CMUL(d1r[3], d1i[3], uG0r, uG0i, d0r[1], d0i[1]);
      MAKE_U(14, uH0r, uH0i, uH1r, uH1i);
      // g2[h2*4+h1*2+h0] = u14[h2^h1]*d1[h1*2+h0]
      CMUL(g2r[0], g2i[0], uH0r, uH0i, d1r[0], d1i[0]);
      CMUL(g2r[1], g2i[1], uH0r, uH0i, d1r[1], d1i[1]);
      CMUL(g2r[2], g2i[2], uH1r, uH1i, d1r[2], d1i[2]);
      CMUL(g2r[3], g2i[3], uH1r, uH1i, d1r[3], d1i[3]);
      CMUL(g2r[4], g2i[4], uH1r, uH1i, d1r[0], d1i[0]);
      CMUL(g2r[5], g2i[5], uH1r, uH1i, d1r[1], d1i[1]);
      CMUL(g2r[6], g2i[6], uH0r, uH0i, d1r[2], d1i[2]);
      CMUL(g2r[7], g2i[7], uH0r, uH0i, d1r[3], d1i[3]);
    }
    sfor<16>([&](auto gc_) {
      constexpr int g = decltype(gc_)::value;
      constexpr int h5 = (g >> 3) & 1, h4 = (g >> 2) & 1, h3 = (g >> 1) & 1, h2 = g & 1;
      constexpr int ta = h5 * 2 + h4;
      constexpr int tb = ((h4 ^ h3) << 1) | (h3 ^ h2);
      float g1r_, g1i_;
      CMUL(g1r_, g1i_, TAr[ta], TAi[ta], TBr[tb], TBi[tb]);
      sfor<4>([&](auto tc_) {
        constexpr int t = decltype(tc_)::value;
        constexpr int i7 = (h2 << 2) | t;
        const float re = g1r_ * g2r[i7] - g1i_ * g2i[i7];
        const float im = g1r_ * g2i[i7] + g1i_ * g2r[i7];
        s[g * 4 + t] = plane ? im : re;
      });
    });

    // ---------------- set 1: qubits 10..15 (slot bits 5..0) ----------------
    STAGE(10, 5, l5) STAGE(11, 4, l4) STAGE(12, 3, 0)
    STAGE(13, 2, 0)  STAGE(14, 1, 0)  STAGE(15, 0, 0)

    // ---------------- T1: in-wave lane<->slot transpose ----------------
    const int waveBase = w << 10;
    const int bp = l >> 4;
    const int kk = l & 15;
    sfor<4>([&](auto dc_) {
      constexpr int d = decltype(dc_)::value;
      __syncthreads();
      sfor<16>([&](auto kc_) {
        constexpr int k = decltype(kc_)::value;
        lds[waveBase + k * 64 + (l ^ (k & 12))] = s[16 * d + k];
      });
      __syncthreads();
      const int xb = 16 * (d ^ bp);
      sfor<4>([&](auto jc_) {
        constexpr int j4 = decltype(jc_)::value;
        const int xa = (xb + 4 * j4) ^ (kk & 12);
        const float4 v = *reinterpret_cast<const float4*>(&lds[waveBase + kk * 64 + xa]);
        s[16 * d + 4 * j4 + 0] = v.x;
        s[16 * d + 4 * j4 + 1] = v.y;
        s[16 * d + 4 * j4 + 2] = v.z;
        s[16 * d + 4 * j4 + 3] = v.w;
      });
    });

    // ---------------- set 2: qubits 4..9 (slot bits 5..0) ----------------
    STAGE(4, 5, l5) STAGE(5, 4, l4) STAGE(6, 3, 0)
    STAGE(7, 2, 0)  STAGE(8, 1, 0)  STAGE(9, 0, 0)

    // ---------------- T2: cross-wave swap (wave bits <-> slot bits 5..2) ----------------
    sfor<4>([&](auto cc_) {
      constexpr int c = decltype(cc_)::value;
      __syncthreads();
      sfor<16>([&](auto mc_) {
        constexpr int m = decltype(mc_)::value;
        const int mact = m ^ (l5 << 3) ^ (l4 << 2);   // undo register xor invariant
        lds[(w << 10) + mact * 64 + l] = s[4 * m + c];
      });
      __syncthreads();
      sfor<16>([&](auto gc_) {
        constexpr int g = decltype(gc_)::value;
        s[4 * g + c] = lds[(g << 10) + (w << 6) + l];  // clean: reg == actual from here
      });
    });

    // ---------------- set 3: qubits 0..3 (slot bits 5..2) ----------------
    STAGE(0, 5, 0) STAGE(1, 4, 0) STAGE(2, 3, 0) STAGE(3, 2, 0)

    // ---------------- measurement: partial Walsh fold ----------------
    // Final layout: qubit bits: b0..b3 = slot5..2, b4..b7 = w3..w0, b8,b9 = slot1,0,
    // b10..b15 = l5..l0. Ring-2 absorbed: mask_q = prefix parity.
    float alpha[4], beta[4], gammav[4], deltav[4], epsv[4];
    sfor<4>([&](auto bc_) {
      constexpr int b = decltype(bc_)::value;
      float p0[16];
      sfor<16>([&](auto oc_) {
        constexpr int o = decltype(oc_)::value;
        const float vv = s[16 * b + o]; p0[o] = vv * vv;
      });
      float tt[8], uu[8];
      sfor<8>([&](auto oc_) {
        constexpr int o = decltype(oc_)::value;
        tt[o] = p0[2*o] + p0[2*o+1]; uu[o] = p0[2*o] - p0[2*o+1];
      });
      float ts[4], td[4], ud[4];
      sfor<4>([&](auto oc_) {
        constexpr int o = decltype(oc_)::value;
        ts[o] = tt[2*o] + tt[2*o+1]; td[o] = tt[2*o] - tt[2*o+1]; ud[o] = uu[2*o] - uu[2*o+1];
      });
      float tss[2], tsd[2], tdd[2], udd[2];
      sfor<2>([&](auto oc_) {
        constexpr int o = decltype(oc_)::value;
        tss[o] = ts[2*o] + ts[2*o+1]; tsd[o] = ts[2*o] - ts[2*o+1];
        tdd[o] = td[2*o] - td[2*o+1]; udd[o] = ud[2*o] - ud[2*o+1];
      });
      alpha[b]  = tss[0] + tss[1];
      beta[b]   = tss[0] - tss[1];
      gammav[b] = tsd[0] - tsd[1];
      deltav[b] = tdd[0] - tdd[1];
      epsv[b]   = udd[0] - udd[1];
    });
    const float TA_ = (alpha[0]  - alpha[1])  - (alpha[2]  - alpha[3]);
    const float TB_ = (beta[0]   - beta[1])   - (beta[2]   - beta[3]);
    const float TC_ = (gammav[0] - gammav[1]) - (gammav[2] - gammav[3]);
    const float TD_ = (deltav[0] - deltav[1]) - (deltav[2] - deltav[3]);
    const float TE_ = (epsv[0]   - epsv[1])   - (epsv[2]   - epsv[3]);
    const float TF_ = (epsv[0]   - epsv[1])   + (epsv[2]   - epsv[3]);

    const int pw1 = w3, pw2 = w3 ^ w2b, pw3 = w3 ^ w2b ^ w1b, pw4 = w3 ^ w2b ^ w1b ^ w0b;
    const int pl1 = l5, pl2 = pl1 ^ l4, pl3 = pl2 ^ l3, pl4 = pl3 ^ l2, pl5 = pl4 ^ l1, pl6 = pl5 ^ l0;

    float part[16];
    part[0]  = (pw4 ^ pl6) ? -TF_ : TF_;
    part[1]  = TA_;
    part[2]  = TB_;
    part[3]  = TC_;
    part[4]  = pw1 ? -TC_ : TC_;
    part[5]  = pw2 ? -TC_ : TC_;
    part[6]  = pw3 ? -TC_ : TC_;
    part[7]  = pw4 ? -TC_ : TC_;
    part[8]  = pw4 ? -TD_ : TD_;
    part[9]  = pw4 ? -TE_ : TE_;
    part[10] = (pw4 ^ pl1) ? -TE_ : TE_;
    part[11] = (pw4 ^ pl2) ? -TE_ : TE_;
    part[12] = (pw4 ^ pl3) ? -TE_ : TE_;
    part[13] = (pw4 ^ pl4) ? -TE_ : TE_;
    part[14] = (pw4 ^ pl5) ? -TE_ : TE_;
    part[15] = (pw4 ^ pl6) ? -TE_ : TE_;

    // ---------------- block reduction: wave q reduces output q ----------------
    __syncthreads();
    sfor<16>([&](auto qc_) {
      constexpr int q = decltype(qc_)::value;
      lds[(w << 10) + (q << 6) + l] = part[q];
    });
    __syncthreads();
    float v = 0.0f;
    #pragma unroll
    for (int w2_ = 0; w2_ < 16; ++w2_)
      v += lds[(w2_ << 10) + (w << 6) + l];
    #pragma unroll
    for (int off = 32; off >= 1; off >>= 1)
      v += __shfl_xor(v, off, 64);
    acc += v;
  }

  if (l == 0) out[sample * NQ + w] = acc;
}

extern "C" void kernel_launch(void* const* d_in, const int* in_sizes, int n_in,
                              void* d_out, int out_size, void* d_ws, size_t ws_size,
                              hipStream_t stream) {
  (void)in_sizes; (void)n_in; (void)d_ws; (void)ws_size; (void)out_size;
  const float* x = (const float*)d_in[0];       // (512, 16) fp32
  const float* params = (const float*)d_in[1];  // (32,) fp32
  float* out = (float*)d_out;                   // (512, 16) fp32
  hipLaunchKernelGGL(qsim_kernel, dim3(512), dim3(1024), 0, stream, x, params, out);
}